// Round 13
// baseline (141.965 us; speedup 1.0000x reference)
//
#include <hip/hip_runtime.h>
#include <hip/hip_bf16.h>

#define BB 32
#define CPD 64
#define TT 4096
#define INDIM 256
#define HH 128
#define WW 128
#define CH 4
#define WARM 16
#define TANH_SC 2.885390081777927f   // 2*log2(e): folded into M and W_hh so tanh needs no mul

typedef __attribute__((ext_vector_type(8)))  short short8;
typedef __attribute__((ext_vector_type(4)))  float f32x4;
typedef __attribute__((ext_vector_type(16))) float f32x16;

// tanh(x) with pre-scaled input zp = 2*log2e*x: 1 - 2/(2^zp + 1). No div, no mul.
__device__ __forceinline__ float tanh_s(float zp){
    float e = exp2f(zp);
    float r = __builtin_amdgcn_rcpf(e + 1.0f);
    return fmaf(-2.0f, r, 1.0f);
}
__device__ __forceinline__ unsigned cvtpk(float lo, float hi){
    unsigned r;
    asm("v_cvt_pk_bf16_f32 %0, %1, %2" : "=v"(r) : "v"(lo), "v"(hi));
    return r;
}
// 16x16x32 stationary A-frags (for k_out), UNSCALED
__device__ __forceinline__ void load_Afrags(const float* __restrict__ Wsrc,
                                            int m, int lg, short8 Wf[8][4]){
    #pragma unroll
    for (int tt = 0; tt < 8; ++tt){
        const float* wrow = &Wsrc[(16*tt + m)*HH + 8*lg];
        #pragma unroll
        for (int kc = 0; kc < 4; ++kc){
            f32x4 w0 = *(const f32x4*)(wrow + 32*kc);
            f32x4 w1 = *(const f32x4*)(wrow + 32*kc + 4);
            uint4 u;
            u.x = cvtpk(w0[0], w0[1]);
            u.y = cvtpk(w0[2], w0[3]);
            u.z = cvtpk(w1[0], w1[1]);
            u.w = cvtpk(w1[2], w1[3]);
            Wf[tt][kc] = __builtin_bit_cast(short8, u);
        }
    }
}

// K1: M[c][h] = 2*log2e * sum_i proj[c,i]*w_ih[h,i]  (scale folded here, free)
__global__ __launch_bounds__(256) void k_proj(const float* __restrict__ proj,
                                              const float* __restrict__ w_ih,
                                              float* __restrict__ M){
    int g = blockIdx.x*256 + threadIdx.x;
    int c = g >> 7, h = g & 127;
    float acc = 0.f;
    #pragma unroll 8
    for (int i = 0; i < INDIM; i += 4){
        float4 p = *(const float4*)&proj[c*INDIM + i];
        float4 q = *(const float4*)&w_ih[h*INDIM + i];
        acc = fmaf(p.x, q.x, acc);
        acc = fmaf(p.y, q.y, acc);
        acc = fmaf(p.z, q.z, acc);
        acc = fmaf(p.w, q.w, acc);
    }
    M[g] = acc * TANH_SC;
}

// K2: xwb[t][b][hp] = packed bf16 pair of (scaled) xw — UNCHANGED
__global__ __launch_bounds__(256) void k_xw(const float* __restrict__ control,
                                            const float* __restrict__ M,
                                            unsigned* __restrict__ xwb){
    __shared__ float ct[CPD][64];
    __shared__ float Ml[CPD][HH];
    int b  = blockIdx.y;
    int t0 = blockIdx.x * 64;
    int tid = threadIdx.x;

    #pragma unroll
    for (int k = 0; k < 32; ++k){
        int f = tid + k*256;
        ((float*)Ml)[f] = M[f];
    }
    #pragma unroll
    for (int k = 0; k < 16; ++k){
        int f = tid + k*256;
        int c = f >> 6, t = f & 63;
        ct[c][t] = control[((size_t)b*CPD + c)*TT + t0 + t];
    }
    __syncthreads();

    int hp = tid & 63;
    int tq = tid >> 6;
    float a0[16], a1[16];
    #pragma unroll
    for (int j = 0; j < 16; ++j){ a0[j] = 0.f; a1[j] = 0.f; }

    for (int c = 0; c < CPD; ++c){
        float2 mv = *(const float2*)&Ml[c][2*hp];
        const float* cr = &ct[c][tq*16];
        #pragma unroll
        for (int j = 0; j < 16; j += 4){
            float4 c4 = *(const float4*)&cr[j];
            a0[j+0] = fmaf(mv.x, c4.x, a0[j+0]); a1[j+0] = fmaf(mv.y, c4.x, a1[j+0]);
            a0[j+1] = fmaf(mv.x, c4.y, a0[j+1]); a1[j+1] = fmaf(mv.y, c4.y, a1[j+1]);
            a0[j+2] = fmaf(mv.x, c4.z, a0[j+2]); a1[j+2] = fmaf(mv.y, c4.z, a1[j+2]);
            a0[j+3] = fmaf(mv.x, c4.w, a0[j+3]); a1[j+3] = fmaf(mv.y, c4.w, a1[j+3]);
        }
    }
    #pragma unroll
    for (int j = 0; j < 16; ++j){
        int t = t0 + tq*16 + j;
        xwb[((size_t)t*BB + b)*64 + hp] = cvtpk(a0[j], a1[j]);
    }
}

// expand 4 bf16-pair uint2s (one acc tile's lane slice) element-wise into f32x16
__device__ __forceinline__ void init_tile(const unsigned* __restrict__ p, f32x16& a){
    #pragma unroll
    for (int m = 0; m < 4; ++m){
        uint2 u = *(const uint2*)(p + 4*m);
        a[4*m+0] = __uint_as_float(u.x << 16);
        a[4*m+1] = __uint_as_float(u.x & 0xFFFF0000u);
        a[4*m+2] = __uint_as_float(u.y << 16);
        a[4*m+3] = __uint_as_float(u.y & 0xFFFF0000u);
    }
}

// K3: 32-wide MFMA scan, zero-LDS loop, register-pressure-tamed.
// grid(1024), block 64. Wave = chunk c (XCD-contiguous), 32 batches as MFMA
// cols (32x32x16). C-init = element-wise bf16 expand of xw (no shuffles, no
// double-buffer: loads at point of use, L2-resident). Epilogue fused PER TILE
// (tanh -> cvt_pk -> permlane32_swap -> Bf): pk live = 8 regs, not 32.
// Peak live ~= Wf 128 + acc 64 + Bf 32 + pk 8 + addr ~ 240 < 256.
__global__ __launch_bounds__(64, 1) void k_scan(const unsigned* __restrict__ xwb,
                                                const float* __restrict__ w_hh,
                                                char* __restrict__ hsb){
    const int lane = threadIdx.x;
    const int b  = lane & 31;
    const int hi = lane >> 5;
    const int c  = (blockIdx.x & 7)*128 + (blockIdx.x >> 3);   // XCD-contiguous chunks

    // A-frags: m=lane&31, k = kt*16 + hi*8 + e; scaled by 2.885
    short8 Wf[4][8];
    #pragma unroll
    for (int tt = 0; tt < 4; ++tt){
        const float* wrow = &w_hh[(tt*32 + b)*HH + hi*8];
        #pragma unroll
        for (int kt = 0; kt < 8; ++kt){
            f32x4 w0 = *(const f32x4*)(wrow + kt*16);
            f32x4 w1 = *(const f32x4*)(wrow + kt*16 + 4);
            uint4 u;
            u.x = cvtpk(w0[0]*TANH_SC, w0[1]*TANH_SC);
            u.y = cvtpk(w0[2]*TANH_SC, w0[3]*TANH_SC);
            u.z = cvtpk(w1[0]*TANH_SC, w1[1]*TANH_SC);
            u.w = cvtpk(w1[2]*TANH_SC, w1[3]*TANH_SC);
            Wf[tt][kt] = __builtin_bit_cast(short8, u);
        }
    }

    short8 Bf[8];                       // H state as B-frags (h0 = 0)
    {
        uint4 z = {0u,0u,0u,0u};
        #pragma unroll
        for (int kt = 0; kt < 8; ++kt) Bf[kt] = __builtin_bit_cast(short8, z);
    }

    const int tout = c*CH;
    int tstart = tout - WARM; if (tstart < 0) tstart = 0;
    const int tend = tout + CH;

    const unsigned* xb = xwb + b*64 + 2*hi;   // per-lane xw base ([t][b][hp])

    #pragma unroll 1
    for (int t = tstart; t < tend; ++t){
        const unsigned* xt = xb + (size_t)t*2048;
        f32x16 a0, a1, a2, a3;
        init_tile(xt +  0, a0);
        init_tile(xt + 16, a1);
        init_tile(xt + 32, a2);
        init_tile(xt + 48, a3);
        #pragma unroll
        for (int kt = 0; kt < 8; ++kt){ // 4 independent M-tile chains, K-depth 8
            a0 = __builtin_amdgcn_mfma_f32_32x32x16_bf16(Wf[0][kt], Bf[kt], a0, 0,0,0);
            a1 = __builtin_amdgcn_mfma_f32_32x32x16_bf16(Wf[1][kt], Bf[kt], a1, 0,0,0);
            a2 = __builtin_amdgcn_mfma_f32_32x32x16_bf16(Wf[2][kt], Bf[kt], a2, 0,0,0);
            a3 = __builtin_amdgcn_mfma_f32_32x32x16_bf16(Wf[3][kt], Bf[kt], a3, 0,0,0);
        }
        // fused per-tile epilogue: tanh -> pack -> permlane swap -> Bf
#define EPI(AT, TL)                                                 \
        {  unsigned pk0, pk1, pk2, pk3, pk4, pk5, pk6, pk7;         \
           { float h0 = tanh_s(AT[0]),  h1 = tanh_s(AT[1]);         \
             float h2 = tanh_s(AT[2]),  h3 = tanh_s(AT[3]);         \
             pk0 = cvtpk(h0,h1); pk1 = cvtpk(h2,h3); }              \
           { float h0 = tanh_s(AT[4]),  h1 = tanh_s(AT[5]);         \
             float h2 = tanh_s(AT[6]),  h3 = tanh_s(AT[7]);         \
             pk2 = cvtpk(h0,h1); pk3 = cvtpk(h2,h3); }              \
           { float h0 = tanh_s(AT[8]),  h1 = tanh_s(AT[9]);         \
             float h2 = tanh_s(AT[10]), h3 = tanh_s(AT[11]);        \
             pk4 = cvtpk(h0,h1); pk5 = cvtpk(h2,h3); }              \
           { float h0 = tanh_s(AT[12]), h1 = tanh_s(AT[13]);        \
             float h2 = tanh_s(AT[14]), h3 = tanh_s(AT[15]);        \
             pk6 = cvtpk(h0,h1); pk7 = cvtpk(h2,h3); }              \
           asm("v_permlane32_swap_b32 %0, %1" : "+v"(pk0), "+v"(pk2)); \
           asm("v_permlane32_swap_b32 %0, %1" : "+v"(pk1), "+v"(pk3)); \
           { uint4 u; u.x = pk0; u.y = pk1; u.z = pk2; u.w = pk3;   \
             Bf[2*(TL)]   = __builtin_bit_cast(short8, u); }        \
           asm("v_permlane32_swap_b32 %0, %1" : "+v"(pk4), "+v"(pk6)); \
           asm("v_permlane32_swap_b32 %0, %1" : "+v"(pk5), "+v"(pk7)); \
           { uint4 u; u.x = pk4; u.y = pk5; u.z = pk6; u.w = pk7;   \
             Bf[2*(TL)+1] = __builtin_bit_cast(short8, u); }        \
        }
        EPI(a0,0) EPI(a1,1) EPI(a2,2) EPI(a3,3)
#undef EPI
        if (t >= tout){                 // emit B-frags: 8 x 1KB-contiguous stores
            char* hp_ = hsb + (size_t)t*8192 + lane*16;
            #pragma unroll
            for (int kt = 0; kt < 8; ++kt)
                *(uint4*)(hp_ + kt*1024) = __builtin_bit_cast(uint4, Bf[kt]);
        }
    }
}

// K4: out-projection + sin. grid (TT/16, 2), block 256 (4 waves). UNCHANGED.
__global__ __launch_bounds__(256, 2) void k_out(const char* __restrict__ hsb,
                                                const float* __restrict__ w_out,
                                                float* __restrict__ out){
    __shared__ uint4 st4[4096];         // 64KB
    char* st = (char*)st4;
    const int bg = blockIdx.y;
    const int t0 = blockIdx.x * 16;
    const int tid = threadIdx.x;
    const int lane = tid & 63;
    const int wv   = tid >> 6;
    const int ml   = lane & 15;
    const int lgo  = lane >> 4;

    short8 Wo[8][4];
    load_Afrags(w_out, ml, lgo, Wo);

    #pragma unroll
    for (int k = 0; k < 16; ++k){
        int idx = k*256 + tid;
        int tpr = idx >> 8, rest = idx & 255;
        int kt = rest >> 5, lh = rest & 31;
        const char* g = hsb + (size_t)(t0+tpr)*8192 + kt*1024
                        + (size_t)(bg*16 + (lh & 15) + 32*(lh >> 4))*16;
        uint4 v = *(const uint4*)g;
        int L = (tpr*4096 + kt*512 + lh*16) ^ ((tpr & 7) << 4);
        *(uint4*)&st[L] = v;
    }
    __syncthreads();

    #pragma unroll 1
    for (int i = 0; i < 4; ++i){
        const int s = wv*4 + i;
        const int b = bg*16 + s;
        short8 Bf[4];
        #pragma unroll
        for (int kc = 0; kc < 4; ++kc){
            int L = (ml*4096 + (2*kc + (lgo>>1))*512 + ((lgo&1)*16 + s)*16) ^ ((ml & 7) << 4);
            Bf[kc] = __builtin_bit_cast(short8, *(const uint4*)&st[L]);
        }
        f32x4 o[8];
        #pragma unroll
        for (int tt = 0; tt < 8; ++tt){ f32x4 z = {0.f,0.f,0.f,0.f}; o[tt] = z; }
        #pragma unroll
        for (int kc = 0; kc < 4; ++kc){
            #pragma unroll
            for (int tt = 0; tt < 8; ++tt)
                o[tt] = __builtin_amdgcn_mfma_f32_16x16x32_bf16(Wo[tt][kc], Bf[kc], o[tt], 0,0,0);
        }
        float* orow = out + ((size_t)b*TT + t0 + ml)*HH + 4*lgo;
        #pragma unroll
        for (int tt = 0; tt < 8; ++tt){
            f32x4 a = o[tt];
            a[0] = __sinf(a[0]); a[1] = __sinf(a[1]);
            a[2] = __sinf(a[2]); a[3] = __sinf(a[3]);
            *(f32x4*)(orow + 16*tt) = a;
        }
    }
}

extern "C" void kernel_launch(void* const* d_in, const int* in_sizes, int n_in,
                              void* d_out, int out_size, void* d_ws, size_t ws_size,
                              hipStream_t stream) {
    const float* control = (const float*)d_in[0];
    const float* proj    = (const float*)d_in[1];
    const float* w_ih    = (const float*)d_in[2];
    const float* w_hh    = (const float*)d_in[3];
    const float* w_out   = (const float*)d_in[4];

    float*    M   = (float*)d_ws;                              // 32 KB (scaled)
    unsigned* xwb = (unsigned*)((char*)d_ws + 65536);          // 32 MB bf16 (scaled), time-major
    char*     hsb = (char*)d_ws + 65536 + 33554432;            // 32 MB B-fragment-layout H

    k_proj<<<dim3(32), dim3(256), 0, stream>>>(proj, w_ih, M);
    k_xw  <<<dim3(TT/64, BB), dim3(256), 0, stream>>>(control, M, xwb);
    k_scan<<<dim3(1024), dim3(64), 0, stream>>>(xwb, w_hh, hsb);
    k_out <<<dim3(TT/16, 2), dim3(256), 0, stream>>>(hsb, w_out, (float*)d_out);
}